// Round 1
// baseline (5744.579 us; speedup 1.0000x reference)
//
#include <hip/hip_runtime.h>
#include <stdint.h>

#define IN_DIM 128
#define HID 32

// ---------------- init: zero accumulators, deg = 1 (self-loop) ----------------
__global__ void init_kernel(float* __restrict__ acc1, float* __restrict__ deg,
                            float* __restrict__ acc2, int n) {
    int t = blockIdx.x * blockDim.x + threadIdx.x;
    if (t < n * HID) acc1[t] = 0.f;
    if (t < n) { deg[t] = 1.f; acc2[t] = 0.f; }
}

// ---------------- degree count over edge dst ----------------
__global__ void deg_kernel(const int* __restrict__ dst, float* __restrict__ deg, int e) {
    int t = blockIdx.x * blockDim.x + threadIdx.x;
    if (t < e) atomicAdd(&deg[dst[t]], 1.f);
}

// ---------------- dinv = rsqrt(deg), in place ----------------
__global__ void dinv_kernel(float* __restrict__ deg, int n) {
    int t = blockIdx.x * blockDim.x + threadIdx.x;
    if (t < n) deg[t] = rsqrtf(deg[t]);
}

// ---------------- h1 = x @ W1 (128 -> 32), W1 staged in LDS ----------------
__global__ __launch_bounds__(256) void mm1_kernel(const float* __restrict__ x,
                                                  const float* __restrict__ W1,
                                                  float* __restrict__ h1, int n) {
    __shared__ float Ws[IN_DIM * HID];   // 16 KB
    for (int i = threadIdx.x; i < IN_DIM * HID; i += 256) Ws[i] = W1[i];
    __syncthreads();
    int node = blockIdx.x * 256 + threadIdx.x;
    if (node >= n) return;
    float acc[HID];
#pragma unroll
    for (int j = 0; j < HID; j++) acc[j] = 0.f;
    const float4* xr = (const float4*)(x + (size_t)node * IN_DIM);
#pragma unroll 4
    for (int k4 = 0; k4 < IN_DIM / 4; k4++) {
        float4 xv = xr[k4];
        int k = k4 * 4;
#pragma unroll
        for (int j = 0; j < HID; j++) {
            acc[j] += xv.x * Ws[(k + 0) * HID + j] + xv.y * Ws[(k + 1) * HID + j]
                    + xv.z * Ws[(k + 2) * HID + j] + xv.w * Ws[(k + 3) * HID + j];
        }
    }
    float4* out = (float4*)(h1 + (size_t)node * HID);
#pragma unroll
    for (int q = 0; q < HID / 4; q++) {
        out[q] = make_float4(acc[q * 4 + 0], acc[q * 4 + 1], acc[q * 4 + 2], acc[q * 4 + 3]);
    }
}

// ---------------- layer-1 edge scatter: acc1[dst] += h1[src] * norm ----------------
__global__ void scatter1_kernel(const int* __restrict__ src, const int* __restrict__ dst,
                                const float* __restrict__ dinv, const float* __restrict__ h1,
                                float* __restrict__ acc1, int e) {
    int t = blockIdx.x * blockDim.x + threadIdx.x;
    if (t >= e) return;
    int s = src[t], d = dst[t];
    float nrm = dinv[s] * dinv[d];
    const float4* hs = (const float4*)(h1 + (size_t)s * HID);
    float* ad = acc1 + (size_t)d * HID;
#pragma unroll
    for (int q = 0; q < HID / 4; q++) {
        float4 v = hs[q];
        atomicAdd(ad + q * 4 + 0, v.x * nrm);
        atomicAdd(ad + q * 4 + 1, v.y * nrm);
        atomicAdd(ad + q * 4 + 2, v.z * nrm);
        atomicAdd(ad + q * 4 + 3, v.w * nrm);
    }
}

// ---------------- finish layer 1: + self-loop term + bias, relu (in place on acc1) ----------------
__global__ void finish1_kernel(const float* __restrict__ h1, const float* __restrict__ dinv,
                               const float* __restrict__ b1, float* __restrict__ acc1, int n) {
    int t = blockIdx.x * blockDim.x + threadIdx.x;
    if (t >= n * HID) return;
    int i = t / HID, j = t % HID;
    float di = dinv[i];
    float v = acc1[t] + h1[t] * di * di + b1[j];
    acc1[t] = fmaxf(v, 0.f);
}

// ---------------- h2 = out1 @ W2 (32 -> 1) ----------------
__global__ void mm2_kernel(const float* __restrict__ h, const float* __restrict__ W2,
                           float* __restrict__ h2, int n) {
    __shared__ float w2s[HID];
    if (threadIdx.x < HID) w2s[threadIdx.x] = W2[threadIdx.x];
    __syncthreads();
    int i = blockIdx.x * blockDim.x + threadIdx.x;
    if (i >= n) return;
    const float4* hr = (const float4*)(h + (size_t)i * HID);
    float s = 0.f;
#pragma unroll
    for (int q = 0; q < HID / 4; q++) {
        float4 v = hr[q];
        s += v.x * w2s[q * 4 + 0] + v.y * w2s[q * 4 + 1] + v.z * w2s[q * 4 + 2] + v.w * w2s[q * 4 + 3];
    }
    h2[i] = s;
}

// ---------------- layer-2 edge scatter (scalar) ----------------
__global__ void scatter2_kernel(const int* __restrict__ src, const int* __restrict__ dst,
                                const float* __restrict__ dinv, const float* __restrict__ h2,
                                float* __restrict__ acc2, int e) {
    int t = blockIdx.x * blockDim.x + threadIdx.x;
    if (t >= e) return;
    int s = src[t], d = dst[t];
    atomicAdd(&acc2[d], h2[s] * dinv[s] * dinv[d]);
}

// ---------------- finish layer 2: + self-loop + bias, sigmoid -> out ----------------
__global__ void finish2_kernel(const float* __restrict__ h2, const float* __restrict__ dinv,
                               const float* __restrict__ b2, const float* __restrict__ acc2,
                               float* __restrict__ out, int n) {
    int i = blockIdx.x * blockDim.x + threadIdx.x;
    if (i >= n) return;
    float di = dinv[i];
    float v = acc2[i] + h2[i] * di * di + b2[0];
    out[i] = 1.f / (1.f + expf(-v));
}

extern "C" void kernel_launch(void* const* d_in, const int* in_sizes, int n_in,
                              void* d_out, int out_size, void* d_ws, size_t ws_size,
                              hipStream_t stream) {
    const float* x  = (const float*)d_in[0];
    const int*   ei = (const int*)d_in[1];   // [2, E] int32 (harness canonicalizes int64->int32)
    const float* W1 = (const float*)d_in[2];
    const float* b1 = (const float*)d_in[3];
    const float* W2 = (const float*)d_in[4];
    const float* b2 = (const float*)d_in[5];
    float* out = (float*)d_out;

    const int n = in_sizes[0] / IN_DIM;       // 100000
    const int e = in_sizes[1] / 2;            // 3200000
    const int* src = ei;
    const int* dst = ei + e;

    // workspace layout (floats). All offsets are multiples of 4 floats (16B) since n % 4 == 0.
    float* ws   = (float*)d_ws;
    float* dinv = ws;                          // n   (deg first, then rsqrt in place)
    float* h1   = dinv + n;                    // n*HID
    float* acc1 = h1 + (size_t)n * HID;        // n*HID
    float* h2   = acc1 + (size_t)n * HID;      // n
    float* acc2 = h2 + n;                      // n

    const int B = 256;
    int gN   = (n + B - 1) / B;
    int gNH  = (n * HID + B - 1) / B;
    int gE   = (e + B - 1) / B;

    init_kernel<<<gNH, B, 0, stream>>>(acc1, dinv, acc2, n);
    deg_kernel<<<gE, B, 0, stream>>>(dst, dinv, e);
    dinv_kernel<<<gN, B, 0, stream>>>(dinv, n);
    mm1_kernel<<<gN, B, 0, stream>>>(x, W1, h1, n);
    scatter1_kernel<<<gE, B, 0, stream>>>(src, dst, dinv, h1, acc1, e);
    finish1_kernel<<<gNH, B, 0, stream>>>(h1, dinv, b1, acc1, n);
    mm2_kernel<<<gN, B, 0, stream>>>(acc1, W2, h2, n);
    scatter2_kernel<<<gE, B, 0, stream>>>(src, dst, dinv, h2, acc2, e);
    finish2_kernel<<<gN, B, 0, stream>>>(h2, dinv, b2, acc2, out, n);
}

// Round 2
// 739.381 us; speedup vs baseline: 7.7694x; 7.7694x over previous
//
#include <hip/hip_runtime.h>
#include <stdint.h>

#define IN_DIM 128
#define HID 32

// ---------------- init: zero degree histogram ----------------
__global__ void init_kernel(int* __restrict__ deg_i, int n) {
    int t = blockIdx.x * blockDim.x + threadIdx.x;
    if (t < n) deg_i[t] = 0;
}

// ---------------- degree count over edge dst (int atomics) ----------------
__global__ void deg_kernel(const int* __restrict__ dst, int* __restrict__ deg_i, int e) {
    int t = blockIdx.x * blockDim.x + threadIdx.x;
    if (t < e) atomicAdd(&deg_i[dst[t]], 1);
}

// ---------------- scan step 1: per-256-block exclusive scan + block sums ----------------
__global__ __launch_bounds__(256) void scan1_kernel(const int* __restrict__ deg_i,
                                                    int* __restrict__ row_off,
                                                    int* __restrict__ bsum, int n) {
    __shared__ int s[256];
    int gid = blockIdx.x * 256 + threadIdx.x;
    int v = (gid < n) ? deg_i[gid] : 0;
    s[threadIdx.x] = v;
    __syncthreads();
    for (int off = 1; off < 256; off <<= 1) {
        int t = (threadIdx.x >= off) ? s[threadIdx.x - off] : 0;
        __syncthreads();
        s[threadIdx.x] += t;
        __syncthreads();
    }
    if (gid < n) row_off[gid] = s[threadIdx.x] - v;   // exclusive within block
    if (threadIdx.x == 255) bsum[blockIdx.x] = s[255];
}

// ---------------- scan step 2: serial scan of block sums (nb ~ 391, trivial) ----------------
__global__ void scan2_kernel(int* __restrict__ bsum, int nb) {
    if (threadIdx.x == 0 && blockIdx.x == 0) {
        int run = 0;
        for (int i = 0; i < nb; i++) { int t = bsum[i]; bsum[i] = run; run += t; }
    }
}

// ---------------- scan step 3: finalize row_off/cursor, dinv = rsqrt(deg+1) ----------------
__global__ __launch_bounds__(256) void scan3_kernel(int* __restrict__ row_off,
                                                    int* __restrict__ cursor,
                                                    const int* __restrict__ bsum,
                                                    const int* __restrict__ deg_i,
                                                    float* __restrict__ dinv, int n, int e) {
    int gid = blockIdx.x * 256 + threadIdx.x;
    if (gid < n) {
        int ro = row_off[gid] + bsum[blockIdx.x];
        row_off[gid] = ro;
        cursor[gid] = ro;
        dinv[gid] = rsqrtf((float)deg_i[gid] + 1.0f);   // +1 self-loop
    }
    if (gid == n) row_off[n] = e;
}

// ---------------- fill CSR: csr_src[pos] = src, bucketed by dst ----------------
__global__ void fill_kernel(const int* __restrict__ src, const int* __restrict__ dst,
                            int* __restrict__ cursor, int* __restrict__ csr_src, int e) {
    int t = blockIdx.x * blockDim.x + threadIdx.x;
    if (t >= e) return;
    int d = dst[t];
    int pos = atomicAdd(&cursor[d], 1);
    csr_src[pos] = src[t];
}

// ---------------- h1 = x @ W1 (128 -> 32), W1 staged in LDS ----------------
__global__ __launch_bounds__(256) void mm1_kernel(const float* __restrict__ x,
                                                  const float* __restrict__ W1,
                                                  float* __restrict__ h1, int n) {
    __shared__ float Ws[IN_DIM * HID];   // 16 KB
    for (int i = threadIdx.x; i < IN_DIM * HID; i += 256) Ws[i] = W1[i];
    __syncthreads();
    int node = blockIdx.x * 256 + threadIdx.x;
    if (node >= n) return;
    float acc[HID];
#pragma unroll
    for (int j = 0; j < HID; j++) acc[j] = 0.f;
    const float4* xr = (const float4*)(x + (size_t)node * IN_DIM);
#pragma unroll 4
    for (int k4 = 0; k4 < IN_DIM / 4; k4++) {
        float4 xv = xr[k4];
        int k = k4 * 4;
#pragma unroll
        for (int j = 0; j < HID; j++) {
            acc[j] += xv.x * Ws[(k + 0) * HID + j] + xv.y * Ws[(k + 1) * HID + j]
                    + xv.z * Ws[(k + 2) * HID + j] + xv.w * Ws[(k + 3) * HID + j];
        }
    }
    float4* out = (float4*)(h1 + (size_t)node * HID);
#pragma unroll
    for (int q = 0; q < HID / 4; q++) {
        out[q] = make_float4(acc[q * 4 + 0], acc[q * 4 + 1], acc[q * 4 + 2], acc[q * 4 + 3]);
    }
}

// ---------------- layer-1 gather + epilogue fused (self term, bias, relu, dot W2) ----------------
// One wave (64 lanes) per dst node. Half-wave = one edge; lane j in [0,32) owns feature j.
__global__ __launch_bounds__(256) void gather1_kernel(const int* __restrict__ row_off,
                                                      const int* __restrict__ csr_src,
                                                      const float* __restrict__ dinv,
                                                      const float* __restrict__ h1,
                                                      const float* __restrict__ b1,
                                                      const float* __restrict__ W2,
                                                      float* __restrict__ h2, int n) {
    int wave = (blockIdx.x * 256 + threadIdx.x) >> 6;
    int lane = threadIdx.x & 63;
    int j = lane & 31;
    int half = lane >> 5;
    if (wave >= n) return;
    int d = wave;
    int beg = row_off[d], end = row_off[d + 1];
    float acc = 0.f;
    for (int p = beg + half; p < end; p += 2) {
        int s = csr_src[p];                              // broadcast within half-wave
        acc += h1[(size_t)s * HID + j] * dinv[s];        // 128B coalesced per half-wave
    }
    acc += __shfl_xor(acc, 32);                          // combine the two halves
    float dd = dinv[d];
    float v = acc * dd + h1[(size_t)d * HID + j] * dd * dd + b1[j];
    v = fmaxf(v, 0.f);
    // fused layer-2 transform: dot(out1_row, W2) across the 32 features
    float pv = v * W2[j];
#pragma unroll
    for (int m = 1; m < 32; m <<= 1) pv += __shfl_xor(pv, m);
    if (lane == 0) h2[d] = pv;
}

// ---------------- layer-2 gather: sum h2[s]*dinv[s], + self, + bias, sigmoid ----------------
// One wave per dst node, 64 edges per iteration.
__global__ __launch_bounds__(256) void gather2_kernel(const int* __restrict__ row_off,
                                                      const int* __restrict__ csr_src,
                                                      const float* __restrict__ dinv,
                                                      const float* __restrict__ h2,
                                                      const float* __restrict__ b2,
                                                      float* __restrict__ out, int n) {
    int wave = (blockIdx.x * 256 + threadIdx.x) >> 6;
    int lane = threadIdx.x & 63;
    if (wave >= n) return;
    int d = wave;
    int beg = row_off[d], end = row_off[d + 1];
    float acc = 0.f;
    for (int p = beg + lane; p < end; p += 64) {
        int s = csr_src[p];                              // coalesced
        acc += h2[s] * dinv[s];                          // random 4B, 0.4MB -> cache-hit
    }
#pragma unroll
    for (int m = 1; m < 64; m <<= 1) acc += __shfl_xor(acc, m);
    if (lane == 0) {
        float dd = dinv[d];
        float v = acc * dd + h2[d] * dd * dd + b2[0];
        out[d] = 1.f / (1.f + expf(-v));
    }
}

extern "C" void kernel_launch(void* const* d_in, const int* in_sizes, int n_in,
                              void* d_out, int out_size, void* d_ws, size_t ws_size,
                              hipStream_t stream) {
    const float* x  = (const float*)d_in[0];
    const int*   ei = (const int*)d_in[1];   // [2, E] int32
    const float* W1 = (const float*)d_in[2];
    const float* b1 = (const float*)d_in[3];
    const float* W2 = (const float*)d_in[4];
    const float* b2 = (const float*)d_in[5];
    float* out = (float*)d_out;

    const int n = in_sizes[0] / IN_DIM;       // 100000
    const int e = in_sizes[1] / 2;            // 3200000
    const int* src = ei;
    const int* dst = ei + e;
    const int nb = (n + 255) / 256;           // scan blocks

    // workspace layout, all chunks 16B-aligned (n % 4 == 0)
    float* h1      = (float*)d_ws;                  // n*HID floats (12.8 MB)
    float* dinv    = h1 + (size_t)n * HID;          // n
    float* h2      = dinv + n;                      // n
    int*   deg_i   = (int*)(h2 + n);                // n
    int*   row_off = deg_i + n;                     // n+4 (padded)
    int*   cursor  = row_off + n + 4;               // n
    int*   bsum    = cursor + n;                    // nb (<1024)
    int*   csr_src = bsum + 1024;                   // e ints (12.8 MB)
    // total ~27.6 MB

    const int B = 256;
    int gN  = (n + B - 1) / B;
    int gN1 = (n + 1 + B - 1) / B;
    int gE  = (e + B - 1) / B;
    int gW  = (n + 3) / 4;                    // wave-per-node kernels (4 waves/block)

    init_kernel<<<gN, B, 0, stream>>>(deg_i, n);
    deg_kernel<<<gE, B, 0, stream>>>(dst, deg_i, e);
    scan1_kernel<<<nb, B, 0, stream>>>(deg_i, row_off, bsum, n);
    scan2_kernel<<<1, 64, 0, stream>>>(bsum, nb);
    scan3_kernel<<<gN1, B, 0, stream>>>(row_off, cursor, bsum, deg_i, dinv, n, e);
    fill_kernel<<<gE, B, 0, stream>>>(src, dst, cursor, csr_src, e);
    mm1_kernel<<<gN, B, 0, stream>>>(x, W1, h1, n);
    gather1_kernel<<<gW, B, 0, stream>>>(row_off, csr_src, dinv, h1, b1, W2, h2, n);
    gather2_kernel<<<gW, B, 0, stream>>>(row_off, csr_src, dinv, h2, b2, out, n);
}